// Round 22
// baseline (702.709 us; speedup 1.0000x reference)
//
#include <hip/hip_runtime.h>
#include <stdint.h>

typedef _Float16 f16;
typedef __attribute__((ext_vector_type(8))) _Float16 f16x8;
typedef __attribute__((ext_vector_type(4))) _Float16 f16x4;
typedef __attribute__((ext_vector_type(2))) __fp16 fp16x2;
typedef __attribute__((ext_vector_type(4))) float f32x4;
typedef __attribute__((ext_vector_type(16))) float f32x16;
typedef __attribute__((ext_vector_type(4))) unsigned u32x4;

// async global->LDS, 16B per lane. LDS dest is wave-uniform base (+lane*16 in HW).
__device__ __forceinline__ void gload16(void* lds, const void* gc) {
  void* g = const_cast<void*>(gc);
  __builtin_amdgcn_global_load_lds((__attribute__((address_space(1))) void*)g,
                                   (__attribute__((address_space(3))) void*)lds,
                                   16, 0, 0);
}

__device__ __forceinline__ unsigned pkrtz(float a, float b) {
  union { fp16x2 h; unsigned u; } c;
  c.h = __builtin_amdgcn_cvt_pkrtz(a, b);
  return c.u;
}

// ---------------- f32 -> f16 cast (plain) ----------------
__global__ __launch_bounds__(256) void k_cast(const float* __restrict__ in,
                                              f16* __restrict__ out, int n4) {
  int stride = gridDim.x * blockDim.x;
  for (int i = blockIdx.x * blockDim.x + threadIdx.x; i < n4; i += stride) {
    float4 v = ((const float4*)in)[i];
    f16x4 o;
    o[0] = (f16)v.x; o[1] = (f16)v.y; o[2] = (f16)v.z; o[3] = (f16)v.w;
    ((f16x4*)out)[i] = o;
  }
}

// 4 independent cast jobs selected by blockIdx.y (equal sizes)
__global__ __launch_bounds__(256) void k_cast4(const float* __restrict__ s0, const float* __restrict__ s1,
                                               const float* __restrict__ s2, const float* __restrict__ s3,
                                               f16* __restrict__ d0, f16* __restrict__ d1,
                                               f16* __restrict__ d2, f16* __restrict__ d3, int n4) {
  const int which = blockIdx.y;
  const float* in = which == 0 ? s0 : which == 1 ? s1 : which == 2 ? s2 : s3;
  f16* out = which == 0 ? d0 : which == 1 ? d1 : which == 2 ? d2 : d3;
  int stride = gridDim.x * blockDim.x;
  for (int i = blockIdx.x * blockDim.x + threadIdx.x; i < n4; i += stride) {
    float4 v = ((const float4*)in)[i];
    f16x4 o;
    o[0] = (f16)v.x; o[1] = (f16)v.y; o[2] = (f16)v.z; o[3] = (f16)v.w;
    ((f16x4*)out)[i] = o;
  }
}

// 2 independent cast jobs selected by blockIdx.y
__global__ __launch_bounds__(256) void k_cast2w(const float* __restrict__ s0, const float* __restrict__ s1,
                                                f16* __restrict__ d0, f16* __restrict__ d1, int n4) {
  const int which = blockIdx.y;
  const float* in = which == 0 ? s0 : s1;
  f16* out = which == 0 ? d0 : d1;
  int stride = gridDim.x * blockDim.x;
  for (int i = blockIdx.x * blockDim.x + threadIdx.x; i < n4; i += stride) {
    float4 v = ((const float4*)in)[i];
    f16x4 o;
    o[0] = (f16)v.x; o[1] = (f16)v.y; o[2] = (f16)v.z; o[3] = (f16)v.w;
    ((f16x4*)out)[i] = o;
  }
}

// ---------------- V transpose: [BH][L][128] -> [BH][128][L] ----------------
__global__ __launch_bounds__(256) void k_transpose_v(const f16* __restrict__ vp,
                                                     f16* __restrict__ vt) {
  __shared__ __attribute__((aligned(16))) f16 tile[64][66];
  const int lt = blockIdx.x, dt = blockIdx.y, bh = blockIdx.z;
  const int t = threadIdx.x;
  const int r = t >> 3, c = 8 * (t & 7);
  const f16* src = vp + ((size_t)bh * 2048 + lt * 64) * 128 + dt * 64;
#pragma unroll
  for (int i = 0; i < 2; ++i) {
    union { f16x8 v; unsigned u[4]; } uu;
    uu.v = *(const f16x8*)&src[(size_t)(i * 32 + r) * 128 + c];
#pragma unroll
    for (int j = 0; j < 4; ++j)
      *(unsigned*)&tile[i * 32 + r][c + 2 * j] = uu.u[j];
  }
  __syncthreads();
  f16* dst = vt + ((size_t)bh * 128 + dt * 64) * 2048 + lt * 64;
#pragma unroll
  for (int i = 0; i < 2; ++i) {
    const int dr = i * 32 + r;
    f16x8 o;
#pragma unroll
    for (int e = 0; e < 8; ++e) o[e] = tile[c + e][dr];
    *(f16x8*)&dst[(size_t)dr * 2048 + c] = o;
  }
}

// ---------------- final fuse: out = f32(x1b) + p0 + p1 ----------------
__global__ __launch_bounds__(256) void k_fuseout(const f16* __restrict__ x1b,
                                                 const float* __restrict__ p0,
                                                 const float* __restrict__ p1,
                                                 float* __restrict__ out, int n4) {
  int stride = gridDim.x * blockDim.x;
  for (int i = blockIdx.x * blockDim.x + threadIdx.x; i < n4; i += stride) {
    float4 a = ((const float4*)p0)[i];
    float4 b = ((const float4*)p1)[i];
    f16x4 xb = ((const f16x4*)x1b)[i];
    float4 o;
    o.x = (float)xb[0] + a.x + b.x;
    o.y = (float)xb[1] + a.y + b.y;
    o.z = (float)xb[2] + a.z + b.z;
    o.w = (float)xb[3] + a.w + b.w;
    ((float4*)out)[i] = o;
  }
}

// ---------------- legacy 128x128 NT GEMM (kept for Wo) ----------------
template <int EPI, int SPLITOUT, int BK>
__global__ __launch_bounds__(256, 4) void gemm_nt(const f16* __restrict__ A,
                                                  const f16* __restrict__ B,
                                                  int Kit, int ld, int N,
                                                  const float* __restrict__ res,
                                                  f16* __restrict__ outb) {
  constexpr int TSZ = 128 * BK;
  constexpr int CH  = 2048;
  constexpr int RPC = CH / BK;
  constexpr int NCH = 128 / RPC;
  constexpr int CW  = BK / 8;
  __shared__ __attribute__((aligned(16))) f16 As[TSZ];
  __shared__ __attribute__((aligned(16))) f16 Bs[TSZ];
  const int t = threadIdx.x;
  const int l = t & 63;
  const int w = t >> 6;
  const int wr = w >> 1, wc = w & 1;

  const int nwg = gridDim.x * gridDim.y;
  const int id = blockIdx.y * gridDim.x + blockIdx.x;
  const int sw = (id & 7) * (nwg >> 3) + (id >> 3);
  const int bn = sw % gridDim.x;
  const int bm = sw / gridDim.x;

  f32x4 acc[4][4] = {};

  const size_t aoff = (size_t)bm * 128 * ld;
  const size_t boff = (size_t)bn * 128 * ld;

  const int sr = t / CW;
  const int sc = 8 * (t % CW);
  const int lbase = w * 512;

  const int lr = l & 15, lq = l >> 4;
  const int nk = Kit / BK;
  for (int kt = 0; kt < nk; ++kt) {
    const size_t gbase = (size_t)kt * BK + (size_t)sr * ld + sc;
#pragma unroll
    for (int j = 0; j < NCH; ++j) {
      gload16(As + j * CH + lbase, A + aoff + (size_t)j * RPC * ld + gbase);
      gload16(Bs + j * CH + lbase, B + boff + (size_t)j * RPC * ld + gbase);
    }
    __syncthreads();
#pragma unroll
    for (int kk = 0; kk < BK / 32; ++kk) {
      f16x8 af[4], bfr[4];
#pragma unroll
      for (int m = 0; m < 4; ++m)
        af[m] = *(const f16x8*)&As[(wr * 64 + m * 16 + lr) * BK + kk * 32 + 8 * lq];
#pragma unroll
      for (int n = 0; n < 4; ++n)
        bfr[n] = *(const f16x8*)&Bs[(wc * 64 + n * 16 + lr) * BK + kk * 32 + 8 * lq];
#pragma unroll
      for (int m = 0; m < 4; ++m)
#pragma unroll
        for (int n = 0; n < 4; ++n)
          acc[m][n] = __builtin_amdgcn_mfma_f32_16x16x32_f16(af[m], bfr[n], acc[m][n], 0, 0, 0);
    }
    __syncthreads();
  }

#pragma unroll
  for (int m = 0; m < 4; ++m) {
#pragma unroll
    for (int r = 0; r < 4; ++r) {
      const int grow = bm * 128 + wr * 64 + m * 16 + lq * 4 + r;
#pragma unroll
      for (int n = 0; n < 4; ++n) {
        const int gcol = bn * 128 + wc * 64 + n * 16 + lr;
        const size_t idx = (size_t)grow * N + gcol;
        outb[idx] = (f16)(res[idx] + acc[m][n][r]);
      }
    }
  }
}

// ---------------- 256x256 BK=64 8-phase pipelined NT GEMM (m201 port) ----------------
template <int EPI, int SPLITOUT>
__global__ __launch_bounds__(512) void gemm9(const f16* __restrict__ A,
                                             const f16* __restrict__ B,
                                             int Kit, int ld, int N,
                                             const float* __restrict__ bias,
                                             float* __restrict__ outf,
                                             float* __restrict__ outf2,
                                             f16* __restrict__ outb,
                                             f16* __restrict__ outb_lo,
                                             f16* __restrict__ outv) {
  __shared__ __attribute__((aligned(16))) f16 As[32768];
  __shared__ __attribute__((aligned(16))) f16 Bs[32768];
  const int t = threadIdx.x;
  const int l = t & 63;
  const int w = t >> 6;
  const int wm = w >> 2, wn = w & 3;

  const int nwg = gridDim.x * gridDim.y;
  const int id = blockIdx.y * gridDim.x + blockIdx.x;
  const int sw = (id & 7) * (nwg >> 3) + (id >> 3);
  const int bn = sw % gridDim.x;
  const int bm = sw / gridDim.x;
  const int k0 = blockIdx.z * Kit;

  const size_t aoff = (size_t)(bm * 256) * ld + k0;
  const size_t boff = (size_t)(bn * 256) * ld + k0;

  const int r0a = t >> 3;
  const int gsw = (t & 7) ^ (r0a & 7);
  const int ldsb = (t >> 6) * 512;

  auto stageA = [&](int tile, int half) {
    const size_t col = (size_t)tile * 64 + gsw * 8;
#pragma unroll
    for (int j = 0; j < 2; ++j)
      gload16(As + (tile & 1) * 16384 + half * 8192 + j * 4096 + ldsb,
              A + aoff + (size_t)(half * 128 + j * 64 + r0a) * ld + col);
  };
  auto stageB = [&](int tile, int half) {
    const size_t col = (size_t)tile * 64 + gsw * 8;
#pragma unroll
    for (int j = 0; j < 2; ++j)
      gload16(Bs + (tile & 1) * 16384 + half * 8192 + j * 4096 + ldsb,
              B + boff + (size_t)(half * 128 + j * 64 + r0a) * ld + col);
  };

  f32x4 acc[8][4] = {};
  f16x8 af[4][2], bf[4][2];

  const int lr = l & 15, lq = l >> 4;

  auto dsA = [&](int buf, int mh) {
#pragma unroll
    for (int m = 0; m < 4; ++m) {
      const int row = mh * 64 + m * 16 + lr;
#pragma unroll
      for (int ks = 0; ks < 2; ++ks) {
        const int g = (ks * 4 + lq) ^ (row & 7);
        af[m][ks] = *(const f16x8*)&As[buf * 16384 + wm * 8192 + row * 64 + g * 8];
      }
    }
  };
  auto dsB = [&](int buf, int nh) {
#pragma unroll
    for (int n2 = 0; n2 < 2; ++n2) {
      const int row = (wn & 1) * 64 + (nh * 2 + n2) * 16 + lr;
#pragma unroll
      for (int ks = 0; ks < 2; ++ks) {
        const int g = (ks * 4 + lq) ^ (row & 7);
        bf[nh * 2 + n2][ks] = *(const f16x8*)&Bs[buf * 16384 + (wn >> 1) * 8192 + row * 64 + g * 8];
      }
    }
  };
  auto mfma16 = [&](int mh, int nh) {
    __builtin_amdgcn_s_setprio(1);
#pragma unroll
    for (int m = 0; m < 4; ++m)
#pragma unroll
      for (int n2 = 0; n2 < 2; ++n2)
#pragma unroll
        for (int ks = 0; ks < 2; ++ks)
          acc[mh * 4 + m][nh * 2 + n2] = __builtin_amdgcn_mfma_f32_16x16x32_f16(
              af[m][ks], bf[nh * 2 + n2][ks], acc[mh * 4 + m][nh * 2 + n2], 0, 0, 0);
    __builtin_amdgcn_s_setprio(0);
  };
#define BAR() __builtin_amdgcn_s_barrier()
#define LGKM() do { asm volatile("s_waitcnt lgkmcnt(0)" ::: "memory"); \
                    __builtin_amdgcn_sched_barrier(0); } while (0)

  const int ntk = Kit >> 6;
  const int nj = ntk >> 1;

  stageA(0, 0); stageA(0, 1); stageB(0, 0); stageB(0, 1);
  stageB(1, 0); stageB(1, 1);
  asm volatile("s_waitcnt vmcnt(4)" ::: "memory");
  BAR();

  for (int j = 0; j < nj; ++j) {
    const int t1 = 2 * j + 1, t2 = 2 * j + 2, t3 = 2 * j + 3;
    const bool last = (j == nj - 1);
    // ph1
    dsA(0, 0); dsB(0, 0);
    stageA(t1, 0);
    BAR(); LGKM(); mfma16(0, 0); BAR();
    // ph2
    dsB(0, 1);
    stageA(t1, 1);
    BAR(); LGKM(); mfma16(0, 1); BAR();
    // ph3
    dsA(0, 1);
    if (t2 < ntk) stageB(t2, 0);
    BAR(); LGKM(); mfma16(1, 0); BAR();
    // ph4
    if (t2 < ntk) stageB(t2, 1);
    BAR(); mfma16(1, 1);
    if (last) { asm volatile("s_waitcnt vmcnt(0)" ::: "memory"); }
    else      { asm volatile("s_waitcnt vmcnt(4)" ::: "memory"); }
    BAR();
    // ph5
    dsA(1, 0); dsB(1, 0);
    if (t2 < ntk) stageA(t2, 0);
    BAR(); LGKM(); mfma16(0, 0); BAR();
    // ph6
    dsB(1, 1);
    if (t2 < ntk) stageA(t2, 1);
    BAR(); LGKM(); mfma16(0, 1); BAR();
    // ph7
    dsA(1, 1);
    if (t3 < ntk) stageB(t3, 0);
    BAR(); LGKM(); mfma16(1, 0); BAR();
    // ph8
    if (t3 < ntk) stageB(t3, 1);
    BAR(); mfma16(1, 1);
    if (last) { asm volatile("s_waitcnt vmcnt(0)" ::: "memory"); }
    else      { asm volatile("s_waitcnt vmcnt(4)" ::: "memory"); }
    BAR();
  }
#undef BAR
#undef LGKM

  const size_t QKS = (size_t)8 << 20;
#pragma unroll
  for (int m = 0; m < 8; ++m) {
#pragma unroll
    for (int r = 0; r < 4; ++r) {
      const int grow = bm * 256 + wm * 128 + m * 16 + lq * 4 + r;
#pragma unroll
      for (int n = 0; n < 4; ++n) {
        const int gcol = bn * 256 + wn * 64 + n * 16 + lr;
        const float v = acc[m][n][r];
        if constexpr (EPI == 0) {
          const int which = gcol >> 11;
          const int hcol = gcol & 2047;
          const int bb = grow >> 11, ll = grow & 2047;
          const int hh = hcol >> 7, dh = hcol & 127;
          const size_t idx = ((size_t)((bb * 16 + hh) * 2048 + ll) << 7) + dh;
          const f16 hv = (f16)v;
          if (which == 2) {
            outv[idx] = hv;
          } else {
            outb[which * QKS + idx] = hv;
            if constexpr (SPLITOUT) outb_lo[which * QKS + idx] = (f16)(v - (float)hv);
          }
        } else if constexpr (EPI == 2) {
          const size_t idx = (size_t)grow * N + gcol;
          outb[idx] = (f16)fmaxf(v + bias[gcol], 0.f);
        } else {
          const size_t idx = (size_t)grow * N + gcol;
          (blockIdx.z ? outf2 : outf)[idx] = v;
        }
      }
    }
  }
}

// ---------------- causal flash attention, 32x32 MFMA, swapped QK^T ----------------
// Pipelined staging: K double-buffered (2x32KB), V single (16KB) = 80KB LDS
// (still 2 blocks/CU; VGPR-bound anyway). Counted-vmcnt ledger per tile:
//   QK(t) from Kbuf[t&1] -> stageK(t+1 -> other buf) [+8]
//   softmax -> vmcnt(8) [retire V(t)] -> BAR -> PV(t) -> BAR
//   stageV(t+1) [+4] -> vmcnt(4) [retire K(t+1)] -> BAR
// Loads stay in flight under softmax/PV instead of a serial vmcnt(0) drain.
// Tail uses clamped indices (redundant stages) for a uniform ledger.
__global__ __launch_bounds__(256) void k_attn(const f16* __restrict__ q_hi,
                                              const f16* __restrict__ q_lo,
                                              const f16* __restrict__ k_hi,
                                              const f16* __restrict__ k_lo,
                                              const f16* __restrict__ vtp,
                                              f16* __restrict__ op) {
  __shared__ __attribute__((aligned(16))) f16 Ks_hi[2 * 8192];
  __shared__ __attribute__((aligned(16))) f16 Ks_lo[2 * 8192];
  __shared__ __attribute__((aligned(16))) f16 Vs[8192];
  const int t = threadIdx.x, l = t & 63, w = t >> 6;
  const int flat = (int)blockIdx.x;
  const int s_ = flat >> 5;
  const int bh = flat & 31;
  const int qb = (s_ < 8) ? (15 - s_) : (s_ - 8);
  const int q0 = qb * 128;
  const int lh = l >> 5, lm = l & 31;
  const int wrow0 = q0 + 32 * w;
  const int myrow = wrow0 + lm;

  const f16* qhp = q_hi + (size_t)bh * 2048 * 128;
  const f16* qlp = q_lo + (size_t)bh * 2048 * 128;
  const f16* khp = k_hi + (size_t)bh * 2048 * 128;
  const f16* klp = k_lo + (size_t)bh * 2048 * 128;
  const f16* vhp = vtp + (size_t)bh * 128 * 2048;

  const int krow = t >> 4, kg = t & 15;
  const int vrow = t >> 3, vg = t & 7;
  const int kgsw = kg ^ (krow & 7);   // source granule for K (i-invariant)
  const int vgsw = vg ^ (vrow & 7);   // source granule for V
  const int wofs = w * 512;           // wave-uniform elem offset (1024 B)

  auto stageK = [&](int tile, int kb) {
#pragma unroll
    for (int i = 0; i < 4; ++i) {
      const size_t ki = (size_t)(tile * 64 + i * 16 + krow) * 128 + 8 * kgsw;
      gload16(Ks_hi + kb * 8192 + i * 2048 + wofs, khp + ki);
      gload16(Ks_lo + kb * 8192 + i * 2048 + wofs, klp + ki);
    }
  };
  auto stageV = [&](int tile) {
#pragma unroll
    for (int i = 0; i < 4; ++i)
      gload16(Vs + i * 2048 + wofs,
              vhp + (size_t)(i * 32 + vrow) * 2048 + tile * 64 + 8 * vgsw);
  };

  f16x8 aqh[8], aql[8];
#pragma unroll
  for (int c = 0; c < 8; ++c) {
    const size_t qi = (size_t)myrow * 128 + c * 16 + 8 * lh;
    aqh[c] = *(const f16x8*)&qhp[qi];
    aql[c] = *(const f16x8*)&qlp[qi];
  }

  f32x16 acc[4] = {};
  float mr = -1e30f, sr = 0.f;

  const int ntile = 2 * qb + 2;
  stageK(0, 0);
  stageV(0);
  asm volatile("s_waitcnt vmcnt(0)" ::: "memory");
  __syncthreads();

  for (int kt = 0; kt < ntile; ++kt) {
    const int kb = kt & 1;
    const bool active = (kt * 64 < wrow0 + 32);
    const int tn = (kt + 1 < ntile) ? (kt + 1) : (ntile - 1);  // clamped next

    f32x16 s0, s1;
    unsigned u[16];
    float ts = 0.f;

    if (active) {
      const f16* Kh = Ks_hi + kb * 8192;
      const f16* Kl = Ks_lo + kb * 8192;
      __builtin_amdgcn_s_setprio(1);
      {
        f32x16 zh = {}, zl = {};
#pragma unroll
        for (int c = 0; c < 8; ++c) {
          const int g = (2 * c + lh) ^ (lm & 7);
          const f16x8 bh_ = *(const f16x8*)&Kh[lm * 128 + 8 * g];
          const f16x8 bl_ = *(const f16x8*)&Kl[lm * 128 + 8 * g];
          zh = __builtin_amdgcn_mfma_f32_32x32x16_f16(bh_, aqh[c], zh, 0, 0, 0);
          zl = __builtin_amdgcn_mfma_f32_32x32x16_f16(bh_, aql[c], zl, 0, 0, 0);
          zl = __builtin_amdgcn_mfma_f32_32x32x16_f16(bl_, aqh[c], zl, 0, 0, 0);
        }
        s0 = zh + zl;
      }
      {
        f32x16 zh = {}, zl = {};
#pragma unroll
        for (int c = 0; c < 8; ++c) {
          const int g = (2 * c + lh) ^ (lm & 7);
          const f16x8 bh_ = *(const f16x8*)&Kh[(32 + lm) * 128 + 8 * g];
          const f16x8 bl_ = *(const f16x8*)&Kl[(32 + lm) * 128 + 8 * g];
          zh = __builtin_amdgcn_mfma_f32_32x32x16_f16(bh_, aqh[c], zh, 0, 0, 0);
          zl = __builtin_amdgcn_mfma_f32_32x32x16_f16(bh_, aql[c], zl, 0, 0, 0);
          zl = __builtin_amdgcn_mfma_f32_32x32x16_f16(bl_, aqh[c], zl, 0, 0, 0);
        }
        s1 = zh + zl;
      }
      __builtin_amdgcn_s_setprio(0);
    }

    // stage next K into the other buffer (its last reads finished tile kt-1,
    // all waves past the end-of-tile barrier). +8 in flight.
    stageK(tn, kb ^ 1);

    if (active) {
      if (kt * 64 + 63 > wrow0) {
#pragma unroll
        for (int j = 0; j < 16; ++j) {
          const int keyl = (j & 3) + 8 * (j >> 2) + 4 * lh;
          if (kt * 64 + keyl > myrow) s0[j] = -1e30f;
          if (kt * 64 + 32 + keyl > myrow) s1[j] = -1e30f;
        }
      }
      float m = -1e30f;
#pragma unroll
      for (int j = 0; j < 16; ++j) m = fmaxf(m, fmaxf(s0[j], s1[j]));
      m = fmaxf(m, __shfl_xor(m, 32));
      if (__any(m > mr + 8.f)) {
        const float mnew = fmaxf(mr, m);
        const float sc = __expf(mr - mnew);
        mr = mnew;
        sr *= sc;
#pragma unroll
        for (int j = 0; j < 16; ++j) {
          const float scj = __shfl(sc, (j & 3) + 8 * (j >> 2) + 4 * lh);
#pragma unroll
          for (int ct = 0; ct < 4; ++ct) acc[ct][j] *= scj;
        }
      }
      // fused exp -> sum -> pack
#pragma unroll
      for (int m2 = 0; m2 < 8; ++m2) {
        const float a0 = __expf(s0[2 * m2] - mr);
        const float a1 = __expf(s0[2 * m2 + 1] - mr);
        const float b0 = __expf(s1[2 * m2] - mr);
        const float b1 = __expf(s1[2 * m2 + 1] - mr);
        ts += (a0 + a1) + (b0 + b1);
        u[m2] = pkrtz(a0, a1);
        u[8 + m2] = pkrtz(b0, b1);
      }
      sr += ts + __shfl_xor(ts, 32);
    }

    // retire V(kt) (oldest 4 of the 12 in flight); K(tn) keeps flying.
    asm volatile("s_waitcnt vmcnt(8)" ::: "memory");
    __syncthreads();

    if (active) {
      unsigned ys[8];
#pragma unroll
      for (int m2 = 0; m2 < 8; ++m2) {
        const int q_ = m2 >> 1, h_ = m2 & 1;
        const unsigned xs = lh ? u[4 * q_ + h_] : u[4 * q_ + 2 + h_];
        ys[m2] = __shfl_xor(xs, 32);
      }
      f16x8 pf[4];
#pragma unroll
      for (int kk = 0; kk < 4; ++kk) {
        union { u32x4 u4; f16x8 h8; } cv;
        if (lh == 0) {
          cv.u4[0] = u[4 * kk];     cv.u4[1] = u[4 * kk + 1];
          cv.u4[2] = ys[2 * kk];    cv.u4[3] = ys[2 * kk + 1];
        } else {
          cv.u4[0] = ys[2 * kk];    cv.u4[1] = ys[2 * kk + 1];
          cv.u4[2] = u[4 * kk + 2]; cv.u4[3] = u[4 * kk + 3];
        }
        pf[kk] = cv.h8;
      }
      __builtin_amdgcn_s_setprio(1);
#pragma unroll
      for (int ct = 0; ct < 4; ++ct) {
        const int dcol = ct * 32 + lm;
#pragma unroll
        for (int kk = 0; kk < 4; ++kk) {
          const int gv = (2 * kk + lh) ^ (dcol & 7);
          const f16x8 bv = *(const f16x8*)&Vs[dcol * 64 + 8 * gv];
          acc[ct] = __builtin_amdgcn_mfma_f32_32x32x16_f16(pf[kk], bv, acc[ct], 0, 0, 0);
        }
      }
      __builtin_amdgcn_s_setprio(0);
    }

    __syncthreads();   // all waves done reading Vs
    stageV(tn);        // +4 in flight
    // retire K(tn) (oldest 8); V(tn) keeps flying into next tile.
    asm volatile("s_waitcnt vmcnt(4)" ::: "memory");
    __syncthreads();
  }
  asm volatile("s_waitcnt vmcnt(0)" ::: "memory");

  const int bb = bh >> 4, hh = bh & 15;
  const float inv = 1.f / sr;
#pragma unroll
  for (int j = 0; j < 16; ++j) {
    const int rl = (j & 3) + 8 * (j >> 2) + 4 * lh;
    const float invj = __shfl(inv, rl);
    const size_t row = (size_t)(bb * 2048 + wrow0 + rl);
#pragma unroll
    for (int ct = 0; ct < 4; ++ct)
      op[row * 2048 + hh * 128 + ct * 32 + lm] = (f16)(acc[ct][j] * invj);
  }
}

extern "C" void kernel_launch(void* const* d_in, const int* in_sizes, int n_in,
                              void* d_out, int out_size, void* d_ws, size_t ws_size,
                              hipStream_t stream) {
  const float* x   = (const float*)d_in[0];
  const float* Wq  = (const float*)d_in[2];
  const float* Wk  = (const float*)d_in[3];
  const float* Wv  = (const float*)d_in[4];
  const float* Wo  = (const float*)d_in[5];
  const float* Wup = (const float*)d_in[6];
  const float* bup = (const float*)d_in[7];
  const float* Wdn = (const float*)d_in[8];
  float* out = (float*)d_out;

  const size_t M1 = 1u << 20;
  f16* W = (f16*)d_ws;
  f16* x_hi    = W + 0 * M1;
  f16* wqkv_hi = W + 8 * M1;
  f16* wo_hi   = W + 20 * M1;
  f16* wup_hi  = W + 24 * M1;
  f16* wdn_hi  = W + 40 * M1;
  f16* q_hi    = W + 56 * M1;
  f16* q_lo    = W + 72 * M1;
  f16* vp      = W + 88 * M1;
  f16* vtb     = W + 96 * M1;
  f16* x1b   = x_hi;
  float* p0  = (float*)(W + 24 * M1);
  f16* hb    = W + 56 * M1;
  float* p1  = (float*)(W + 88 * M1);
  f16* attno = vp;
  if (ws_size < (size_t)104 * M1 * sizeof(f16)) return;  // 208 MB

  auto cg = [](size_t n4) { size_t g = (n4 + 255) / 256; return (unsigned)(g > 2048 ? 2048 : g); };
  dim3 b256(256);
  dim3 b512(512);
  k_cast<<<cg(2 * M1), b256, 0, stream>>>(x, x_hi, (int)(2 * M1));
  k_cast4<<<dim3(cg(1 * M1), 4), b256, 0, stream>>>(
      Wq, Wk, Wv, Wo,
      wqkv_hi, wqkv_hi + 4 * M1, wqkv_hi + 8 * M1, wo_hi, (int)(1 * M1));
  k_cast2w<<<dim3(cg(4 * M1), 2), b256, 0, stream>>>(
      Wup, Wdn, wup_hi, wdn_hi, (int)(4 * M1));

  // fused Q+K+V projection: 256x256 8-phase, split (hi+lo) OUTPUT for Q,K.
  gemm9<0, 1><<<dim3(24, 16), b512, 0, stream>>>(
      x_hi, wqkv_hi, 2048, 2048, 6144,
      nullptr, nullptr, nullptr, q_hi, q_lo, vp);
  k_transpose_v<<<dim3(32, 2, 32), b256, 0, stream>>>(vp, vtb);
  k_attn<<<dim3(512), b256, 0, stream>>>(
      q_hi, q_lo, q_hi + 8 * M1, q_lo + 8 * M1, vtb, attno);
  // Wo projection + residual -> x1b (f16), legacy 128^2 kernel
  gemm_nt<1, 0, 64><<<dim3(16, 32), b256, 0, stream>>>(
      attno, wo_hi, 2048, 2048, 2048, x, x1b);
  // Up + bias + relu -> hb
  gemm9<2, 0><<<dim3(32, 16), b512, 0, stream>>>(
      x1b, wup_hi, 2048, 2048, 8192,
      bup, nullptr, nullptr, hb, nullptr, nullptr);
  // Down, K split 2x -> f32 partials
  gemm9<3, 0><<<dim3(8, 16, 2), b512, 0, stream>>>(
      hb, wdn_hi, 4096, 8192, 2048,
      nullptr, p0, p1, nullptr, nullptr, nullptr);
  // out = f32(x1b) + p0 + p1
  k_fuseout<<<2048, b256, 0, stream>>>(x1b, p0, p1, out, (int)(2 * M1));
}

// Round 23
// 694.102 us; speedup vs baseline: 1.0124x; 1.0124x over previous
//
#include <hip/hip_runtime.h>
#include <stdint.h>

typedef _Float16 f16;
typedef __attribute__((ext_vector_type(8))) _Float16 f16x8;
typedef __attribute__((ext_vector_type(4))) _Float16 f16x4;
typedef __attribute__((ext_vector_type(2))) __fp16 fp16x2;
typedef __attribute__((ext_vector_type(4))) float f32x4;
typedef __attribute__((ext_vector_type(16))) float f32x16;
typedef __attribute__((ext_vector_type(4))) unsigned u32x4;

// async global->LDS, 16B per lane. LDS dest is wave-uniform base (+lane*16 in HW).
__device__ __forceinline__ void gload16(void* lds, const void* gc) {
  void* g = const_cast<void*>(gc);
  __builtin_amdgcn_global_load_lds((__attribute__((address_space(1))) void*)g,
                                   (__attribute__((address_space(3))) void*)lds,
                                   16, 0, 0);
}

__device__ __forceinline__ unsigned pkrtz(float a, float b) {
  union { fp16x2 h; unsigned u; } c;
  c.h = __builtin_amdgcn_cvt_pkrtz(a, b);
  return c.u;
}

// ---------------- f32 -> f16 cast (plain) ----------------
__global__ __launch_bounds__(256) void k_cast(const float* __restrict__ in,
                                              f16* __restrict__ out, int n4) {
  int stride = gridDim.x * blockDim.x;
  for (int i = blockIdx.x * blockDim.x + threadIdx.x; i < n4; i += stride) {
    float4 v = ((const float4*)in)[i];
    f16x4 o;
    o[0] = (f16)v.x; o[1] = (f16)v.y; o[2] = (f16)v.z; o[3] = (f16)v.w;
    ((f16x4*)out)[i] = o;
  }
}

// 4 independent cast jobs selected by blockIdx.y (equal sizes)
__global__ __launch_bounds__(256) void k_cast4(const float* __restrict__ s0, const float* __restrict__ s1,
                                               const float* __restrict__ s2, const float* __restrict__ s3,
                                               f16* __restrict__ d0, f16* __restrict__ d1,
                                               f16* __restrict__ d2, f16* __restrict__ d3, int n4) {
  const int which = blockIdx.y;
  const float* in = which == 0 ? s0 : which == 1 ? s1 : which == 2 ? s2 : s3;
  f16* out = which == 0 ? d0 : which == 1 ? d1 : which == 2 ? d2 : d3;
  int stride = gridDim.x * blockDim.x;
  for (int i = blockIdx.x * blockDim.x + threadIdx.x; i < n4; i += stride) {
    float4 v = ((const float4*)in)[i];
    f16x4 o;
    o[0] = (f16)v.x; o[1] = (f16)v.y; o[2] = (f16)v.z; o[3] = (f16)v.w;
    ((f16x4*)out)[i] = o;
  }
}

// 2 independent cast jobs selected by blockIdx.y
__global__ __launch_bounds__(256) void k_cast2w(const float* __restrict__ s0, const float* __restrict__ s1,
                                                f16* __restrict__ d0, f16* __restrict__ d1, int n4) {
  const int which = blockIdx.y;
  const float* in = which == 0 ? s0 : s1;
  f16* out = which == 0 ? d0 : d1;
  int stride = gridDim.x * blockDim.x;
  for (int i = blockIdx.x * blockDim.x + threadIdx.x; i < n4; i += stride) {
    float4 v = ((const float4*)in)[i];
    f16x4 o;
    o[0] = (f16)v.x; o[1] = (f16)v.y; o[2] = (f16)v.z; o[3] = (f16)v.w;
    ((f16x4*)out)[i] = o;
  }
}

// ---------------- V transpose: [BH][L][128] -> [BH][128][L] ----------------
__global__ __launch_bounds__(256) void k_transpose_v(const f16* __restrict__ vp,
                                                     f16* __restrict__ vt) {
  __shared__ __attribute__((aligned(16))) f16 tile[64][66];
  const int lt = blockIdx.x, dt = blockIdx.y, bh = blockIdx.z;
  const int t = threadIdx.x;
  const int r = t >> 3, c = 8 * (t & 7);
  const f16* src = vp + ((size_t)bh * 2048 + lt * 64) * 128 + dt * 64;
#pragma unroll
  for (int i = 0; i < 2; ++i) {
    union { f16x8 v; unsigned u[4]; } uu;
    uu.v = *(const f16x8*)&src[(size_t)(i * 32 + r) * 128 + c];
#pragma unroll
    for (int j = 0; j < 4; ++j)
      *(unsigned*)&tile[i * 32 + r][c + 2 * j] = uu.u[j];
  }
  __syncthreads();
  f16* dst = vt + ((size_t)bh * 128 + dt * 64) * 2048 + lt * 64;
#pragma unroll
  for (int i = 0; i < 2; ++i) {
    const int dr = i * 32 + r;
    f16x8 o;
#pragma unroll
    for (int e = 0; e < 8; ++e) o[e] = tile[c + e][dr];
    *(f16x8*)&dst[(size_t)dr * 2048 + c] = o;
  }
}

// ---------------- final fuse: out = f32(x1b) + p0 + p1 ----------------
__global__ __launch_bounds__(256) void k_fuseout(const f16* __restrict__ x1b,
                                                 const float* __restrict__ p0,
                                                 const float* __restrict__ p1,
                                                 float* __restrict__ out, int n4) {
  int stride = gridDim.x * blockDim.x;
  for (int i = blockIdx.x * blockDim.x + threadIdx.x; i < n4; i += stride) {
    float4 a = ((const float4*)p0)[i];
    float4 b = ((const float4*)p1)[i];
    f16x4 xb = ((const f16x4*)x1b)[i];
    float4 o;
    o.x = (float)xb[0] + a.x + b.x;
    o.y = (float)xb[1] + a.y + b.y;
    o.z = (float)xb[2] + a.z + b.z;
    o.w = (float)xb[3] + a.w + b.w;
    ((float4*)out)[i] = o;
  }
}

// ---------------- legacy 128x128 NT GEMM (kept for Wo) ----------------
template <int EPI, int SPLITOUT, int BK>
__global__ __launch_bounds__(256, 4) void gemm_nt(const f16* __restrict__ A,
                                                  const f16* __restrict__ B,
                                                  int Kit, int ld, int N,
                                                  const float* __restrict__ res,
                                                  f16* __restrict__ outb) {
  constexpr int TSZ = 128 * BK;
  constexpr int CH  = 2048;
  constexpr int RPC = CH / BK;
  constexpr int NCH = 128 / RPC;
  constexpr int CW  = BK / 8;
  __shared__ __attribute__((aligned(16))) f16 As[TSZ];
  __shared__ __attribute__((aligned(16))) f16 Bs[TSZ];
  const int t = threadIdx.x;
  const int l = t & 63;
  const int w = t >> 6;
  const int wr = w >> 1, wc = w & 1;

  const int nwg = gridDim.x * gridDim.y;
  const int id = blockIdx.y * gridDim.x + blockIdx.x;
  const int sw = (id & 7) * (nwg >> 3) + (id >> 3);
  const int bn = sw % gridDim.x;
  const int bm = sw / gridDim.x;

  f32x4 acc[4][4] = {};

  const size_t aoff = (size_t)bm * 128 * ld;
  const size_t boff = (size_t)bn * 128 * ld;

  const int sr = t / CW;
  const int sc = 8 * (t % CW);
  const int lbase = w * 512;

  const int lr = l & 15, lq = l >> 4;
  const int nk = Kit / BK;
  for (int kt = 0; kt < nk; ++kt) {
    const size_t gbase = (size_t)kt * BK + (size_t)sr * ld + sc;
#pragma unroll
    for (int j = 0; j < NCH; ++j) {
      gload16(As + j * CH + lbase, A + aoff + (size_t)j * RPC * ld + gbase);
      gload16(Bs + j * CH + lbase, B + boff + (size_t)j * RPC * ld + gbase);
    }
    __syncthreads();
#pragma unroll
    for (int kk = 0; kk < BK / 32; ++kk) {
      f16x8 af[4], bfr[4];
#pragma unroll
      for (int m = 0; m < 4; ++m)
        af[m] = *(const f16x8*)&As[(wr * 64 + m * 16 + lr) * BK + kk * 32 + 8 * lq];
#pragma unroll
      for (int n = 0; n < 4; ++n)
        bfr[n] = *(const f16x8*)&Bs[(wc * 64 + n * 16 + lr) * BK + kk * 32 + 8 * lq];
#pragma unroll
      for (int m = 0; m < 4; ++m)
#pragma unroll
        for (int n = 0; n < 4; ++n)
          acc[m][n] = __builtin_amdgcn_mfma_f32_16x16x32_f16(af[m], bfr[n], acc[m][n], 0, 0, 0);
    }
    __syncthreads();
  }

#pragma unroll
  for (int m = 0; m < 4; ++m) {
#pragma unroll
    for (int r = 0; r < 4; ++r) {
      const int grow = bm * 128 + wr * 64 + m * 16 + lq * 4 + r;
#pragma unroll
      for (int n = 0; n < 4; ++n) {
        const int gcol = bn * 128 + wc * 64 + n * 16 + lr;
        const size_t idx = (size_t)grow * N + gcol;
        outb[idx] = (f16)(res[idx] + acc[m][n][r]);
      }
    }
  }
}

// ---------------- 256x256 BK=64 8-phase pipelined NT GEMM (m201 port) ----------------
// 512 thr = 8 waves (2M x 4N), per-wave 128x64 out. LDS 2dbuf x 2half x 128x64
// x {A,B} = 128 KiB, granule-XOR swizzle g'=g^(row&7) (both sides).
// 8 phases per K-tile pair; counted vmcnt(4) at ph4/ph8 only (never 0 in
// steady state); lgkmcnt(0)+sched_barrier before each MFMA cluster.
template <int EPI, int SPLITOUT>
__global__ __launch_bounds__(512) void gemm9(const f16* __restrict__ A,
                                             const f16* __restrict__ B,
                                             int Kit, int ld, int N,
                                             const float* __restrict__ bias,
                                             float* __restrict__ outf,
                                             float* __restrict__ outf2,
                                             f16* __restrict__ outb,
                                             f16* __restrict__ outb_lo,
                                             f16* __restrict__ outv) {
  __shared__ __attribute__((aligned(16))) f16 As[32768];
  __shared__ __attribute__((aligned(16))) f16 Bs[32768];
  const int t = threadIdx.x;
  const int l = t & 63;
  const int w = t >> 6;
  const int wm = w >> 2, wn = w & 3;

  const int nwg = gridDim.x * gridDim.y;
  const int id = blockIdx.y * gridDim.x + blockIdx.x;
  const int sw = (id & 7) * (nwg >> 3) + (id >> 3);
  const int bn = sw % gridDim.x;
  const int bm = sw / gridDim.x;
  const int k0 = blockIdx.z * Kit;

  const size_t aoff = (size_t)(bm * 256) * ld + k0;
  const size_t boff = (size_t)(bn * 256) * ld + k0;

  const int r0a = t >> 3;
  const int gsw = (t & 7) ^ (r0a & 7);
  const int ldsb = (t >> 6) * 512;

  auto stageA = [&](int tile, int half) {
    const size_t col = (size_t)tile * 64 + gsw * 8;
#pragma unroll
    for (int j = 0; j < 2; ++j)
      gload16(As + (tile & 1) * 16384 + half * 8192 + j * 4096 + ldsb,
              A + aoff + (size_t)(half * 128 + j * 64 + r0a) * ld + col);
  };
  auto stageB = [&](int tile, int half) {
    const size_t col = (size_t)tile * 64 + gsw * 8;
#pragma unroll
    for (int j = 0; j < 2; ++j)
      gload16(Bs + (tile & 1) * 16384 + half * 8192 + j * 4096 + ldsb,
              B + boff + (size_t)(half * 128 + j * 64 + r0a) * ld + col);
  };

  f32x4 acc[8][4] = {};
  f16x8 af[4][2], bf[4][2];

  const int lr = l & 15, lq = l >> 4;

  auto dsA = [&](int buf, int mh) {
#pragma unroll
    for (int m = 0; m < 4; ++m) {
      const int row = mh * 64 + m * 16 + lr;
#pragma unroll
      for (int ks = 0; ks < 2; ++ks) {
        const int g = (ks * 4 + lq) ^ (row & 7);
        af[m][ks] = *(const f16x8*)&As[buf * 16384 + wm * 8192 + row * 64 + g * 8];
      }
    }
  };
  auto dsB = [&](int buf, int nh) {
#pragma unroll
    for (int n2 = 0; n2 < 2; ++n2) {
      const int row = (wn & 1) * 64 + (nh * 2 + n2) * 16 + lr;
#pragma unroll
      for (int ks = 0; ks < 2; ++ks) {
        const int g = (ks * 4 + lq) ^ (row & 7);
        bf[nh * 2 + n2][ks] = *(const f16x8*)&Bs[buf * 16384 + (wn >> 1) * 8192 + row * 64 + g * 8];
      }
    }
  };
  auto mfma16 = [&](int mh, int nh) {
    __builtin_amdgcn_s_setprio(1);
#pragma unroll
    for (int m = 0; m < 4; ++m)
#pragma unroll
      for (int n2 = 0; n2 < 2; ++n2)
#pragma unroll
        for (int ks = 0; ks < 2; ++ks)
          acc[mh * 4 + m][nh * 2 + n2] = __builtin_amdgcn_mfma_f32_16x16x32_f16(
              af[m][ks], bf[nh * 2 + n2][ks], acc[mh * 4 + m][nh * 2 + n2], 0, 0, 0);
    __builtin_amdgcn_s_setprio(0);
  };
#define BAR() __builtin_amdgcn_s_barrier()
#define LGKM() do { asm volatile("s_waitcnt lgkmcnt(0)" ::: "memory"); \
                    __builtin_amdgcn_sched_barrier(0); } while (0)

  const int ntk = Kit >> 6;
  const int nj = ntk >> 1;

  stageA(0, 0); stageA(0, 1); stageB(0, 0); stageB(0, 1);
  stageB(1, 0); stageB(1, 1);
  asm volatile("s_waitcnt vmcnt(4)" ::: "memory");
  BAR();

  for (int j = 0; j < nj; ++j) {
    const int t1 = 2 * j + 1, t2 = 2 * j + 2, t3 = 2 * j + 3;
    const bool last = (j == nj - 1);
    // ph1
    dsA(0, 0); dsB(0, 0);
    stageA(t1, 0);
    BAR(); LGKM(); mfma16(0, 0); BAR();
    // ph2
    dsB(0, 1);
    stageA(t1, 1);
    BAR(); LGKM(); mfma16(0, 1); BAR();
    // ph3
    dsA(0, 1);
    if (t2 < ntk) stageB(t2, 0);
    BAR(); LGKM(); mfma16(1, 0); BAR();
    // ph4
    if (t2 < ntk) stageB(t2, 1);
    BAR(); mfma16(1, 1);
    if (last) { asm volatile("s_waitcnt vmcnt(0)" ::: "memory"); }
    else      { asm volatile("s_waitcnt vmcnt(4)" ::: "memory"); }
    BAR();
    // ph5
    dsA(1, 0); dsB(1, 0);
    if (t2 < ntk) stageA(t2, 0);
    BAR(); LGKM(); mfma16(0, 0); BAR();
    // ph6
    dsB(1, 1);
    if (t2 < ntk) stageA(t2, 1);
    BAR(); LGKM(); mfma16(0, 1); BAR();
    // ph7
    dsA(1, 1);
    if (t3 < ntk) stageB(t3, 0);
    BAR(); LGKM(); mfma16(1, 0); BAR();
    // ph8
    if (t3 < ntk) stageB(t3, 1);
    BAR(); mfma16(1, 1);
    if (last) { asm volatile("s_waitcnt vmcnt(0)" ::: "memory"); }
    else      { asm volatile("s_waitcnt vmcnt(4)" ::: "memory"); }
    BAR();
  }
#undef BAR
#undef LGKM

  const size_t QKS = (size_t)8 << 20;
#pragma unroll
  for (int m = 0; m < 8; ++m) {
#pragma unroll
    for (int r = 0; r < 4; ++r) {
      const int grow = bm * 256 + wm * 128 + m * 16 + lq * 4 + r;
#pragma unroll
      for (int n = 0; n < 4; ++n) {
        const int gcol = bn * 256 + wn * 64 + n * 16 + lr;
        const float v = acc[m][n][r];
        if constexpr (EPI == 0) {
          const int which = gcol >> 11;
          const int hcol = gcol & 2047;
          const int bb = grow >> 11, ll = grow & 2047;
          const int hh = hcol >> 7, dh = hcol & 127;
          const size_t idx = ((size_t)((bb * 16 + hh) * 2048 + ll) << 7) + dh;
          const f16 hv = (f16)v;
          if (which == 2) {
            outv[idx] = hv;
          } else {
            outb[which * QKS + idx] = hv;
            if constexpr (SPLITOUT) outb_lo[which * QKS + idx] = (f16)(v - (float)hv);
          }
        } else if constexpr (EPI == 2) {
          const size_t idx = (size_t)grow * N + gcol;
          outb[idx] = (f16)fmaxf(v + bias[gcol], 0.f);
        } else {
          const size_t idx = (size_t)grow * N + gcol;
          (blockIdx.z ? outf2 : outf)[idx] = v;
        }
      }
    }
  }
}

// ---------------- causal flash attention, 32x32 MFMA, swapped QK^T ----------------
// Best measured variant (r19, 154 us): two-phase reg staging (24 transient
// regs), swapped QK^T (in-register softmax), granule-XOR LDS, defer-max.
__global__ __launch_bounds__(256) void k_attn(const f16* __restrict__ q_hi,
                                              const f16* __restrict__ q_lo,
                                              const f16* __restrict__ k_hi,
                                              const f16* __restrict__ k_lo,
                                              const f16* __restrict__ vtp,
                                              f16* __restrict__ op) {
  __shared__ __attribute__((aligned(16))) f16 Ks_hi[64 * 128];
  __shared__ __attribute__((aligned(16))) f16 Ks_lo[64 * 128];
  __shared__ __attribute__((aligned(16))) f16 Vs[128 * 64];
  const int t = threadIdx.x, l = t & 63, w = t >> 6;
  const int flat = (int)blockIdx.x;
  const int s_ = flat >> 5;
  const int bh = flat & 31;
  const int qb = (s_ < 8) ? (15 - s_) : (s_ - 8);
  const int q0 = qb * 128;
  const int lh = l >> 5, lm = l & 31;
  const int wrow0 = q0 + 32 * w;
  const int myrow = wrow0 + lm;

  const f16* qhp = q_hi + (size_t)bh * 2048 * 128;
  const f16* qlp = q_lo + (size_t)bh * 2048 * 128;
  const f16* khp = k_hi + (size_t)bh * 2048 * 128;
  const f16* klp = k_lo + (size_t)bh * 2048 * 128;
  const f16* vhp = vtp + (size_t)bh * 128 * 2048;

  const int krow = t >> 4, kg = t & 15;
  const int vrow = t >> 3, vg = t & 7;

  f16x8 aqh[8], aql[8];
#pragma unroll
  for (int c = 0; c < 8; ++c) {
    const size_t qi = (size_t)myrow * 128 + c * 16 + 8 * lh;
    aqh[c] = *(const f16x8*)&qhp[qi];
    aql[c] = *(const f16x8*)&qlp[qi];
  }

  f32x16 acc[4] = {};
  float mr = -1e30f, sr = 0.f;

  const int ntile = 2 * qb + 2;
  for (int kt = 0; kt < ntile; ++kt) {
    f16x8 kh2[2], kl2[2], v2[2];
#pragma unroll
    for (int i = 0; i < 2; ++i) {
      const size_t ki = (size_t)(kt * 64 + i * 16 + krow) * 128 + 8 * kg;
      kh2[i] = *(const f16x8*)&khp[ki];
      kl2[i] = *(const f16x8*)&klp[ki];
      v2[i] = *(const f16x8*)&vhp[(size_t)(i * 32 + vrow) * 2048 + kt * 64 + 8 * vg];
    }
    __syncthreads();
#pragma unroll
    for (int i = 0; i < 2; ++i) {
      const int kr = i * 16 + krow;
      const int g = kg ^ (kr & 7);
      *(f16x8*)&Ks_hi[kr * 128 + 8 * g] = kh2[i];
      *(f16x8*)&Ks_lo[kr * 128 + 8 * g] = kl2[i];
      const int vr = i * 32 + vrow;
      const int gv = vg ^ (vr & 7);
      *(f16x8*)&Vs[vr * 64 + 8 * gv] = v2[i];
    }
#pragma unroll
    for (int i = 0; i < 2; ++i) {
      const size_t ki = (size_t)(kt * 64 + (i + 2) * 16 + krow) * 128 + 8 * kg;
      kh2[i] = *(const f16x8*)&khp[ki];
      kl2[i] = *(const f16x8*)&klp[ki];
      v2[i] = *(const f16x8*)&vhp[(size_t)((i + 2) * 32 + vrow) * 2048 + kt * 64 + 8 * vg];
    }
#pragma unroll
    for (int i = 0; i < 2; ++i) {
      const int kr = (i + 2) * 16 + krow;
      const int g = kg ^ (kr & 7);
      *(f16x8*)&Ks_hi[kr * 128 + 8 * g] = kh2[i];
      *(f16x8*)&Ks_lo[kr * 128 + 8 * g] = kl2[i];
      const int vr = (i + 2) * 32 + vrow;
      const int gv = vg ^ (vr & 7);
      *(f16x8*)&Vs[vr * 64 + 8 * gv] = v2[i];
    }
    __syncthreads();

    if (kt * 64 >= wrow0 + 32) continue;

    f32x16 s0, s1;
    __builtin_amdgcn_s_setprio(1);
    {
      f32x16 zh = {}, zl = {};
#pragma unroll
      for (int c = 0; c < 8; ++c) {
        const int g = (2 * c + lh) ^ (lm & 7);
        const f16x8 bh_ = *(const f16x8*)&Ks_hi[lm * 128 + 8 * g];
        const f16x8 bl_ = *(const f16x8*)&Ks_lo[lm * 128 + 8 * g];
        zh = __builtin_amdgcn_mfma_f32_32x32x16_f16(bh_, aqh[c], zh, 0, 0, 0);
        zl = __builtin_amdgcn_mfma_f32_32x32x16_f16(bh_, aql[c], zl, 0, 0, 0);
        zl = __builtin_amdgcn_mfma_f32_32x32x16_f16(bl_, aqh[c], zl, 0, 0, 0);
      }
      s0 = zh + zl;
    }
    {
      f32x16 zh = {}, zl = {};
#pragma unroll
      for (int c = 0; c < 8; ++c) {
        const int g = (2 * c + lh) ^ (lm & 7);
        const f16x8 bh_ = *(const f16x8*)&Ks_hi[(32 + lm) * 128 + 8 * g];
        const f16x8 bl_ = *(const f16x8*)&Ks_lo[(32 + lm) * 128 + 8 * g];
        zh = __builtin_amdgcn_mfma_f32_32x32x16_f16(bh_, aqh[c], zh, 0, 0, 0);
        zl = __builtin_amdgcn_mfma_f32_32x32x16_f16(bh_, aql[c], zl, 0, 0, 0);
        zl = __builtin_amdgcn_mfma_f32_32x32x16_f16(bl_, aqh[c], zl, 0, 0, 0);
      }
      s1 = zh + zl;
    }
    __builtin_amdgcn_s_setprio(0);

    if (kt * 64 + 63 > wrow0) {
#pragma unroll
      for (int j = 0; j < 16; ++j) {
        const int keyl = (j & 3) + 8 * (j >> 2) + 4 * lh;
        if (kt * 64 + keyl > myrow) s0[j] = -1e30f;
        if (kt * 64 + 32 + keyl > myrow) s1[j] = -1e30f;
      }
    }

    float m = -1e30f;
#pragma unroll
    for (int j = 0; j < 16; ++j) m = fmaxf(m, fmaxf(s0[j], s1[j]));
    m = fmaxf(m, __shfl_xor(m, 32));
    if (__any(m > mr + 8.f)) {
      const float mnew = fmaxf(mr, m);
      const float sc = __expf(mr - mnew);
      mr = mnew;
      sr *= sc;
#pragma unroll
      for (int j = 0; j < 16; ++j) {
        const float scj = __shfl(sc, (j & 3) + 8 * (j >> 2) + 4 * lh);
#pragma unroll
        for (int ct = 0; ct < 4; ++ct) acc[ct][j] *= scj;
      }
    }
    float p0v[16], p1v[16];
    float ts = 0.f;
#pragma unroll
    for (int j = 0; j < 16; ++j) {
      p0v[j] = __expf(s0[j] - mr);
      p1v[j] = __expf(s1[j] - mr);
      ts += p0v[j] + p1v[j];
    }
    sr += ts + __shfl_xor(ts, 32);

    unsigned u[16];
#pragma unroll
    for (int m2 = 0; m2 < 8; ++m2) {
      u[m2] = pkrtz(p0v[2 * m2], p0v[2 * m2 + 1]);
      u[8 + m2] = pkrtz(p1v[2 * m2], p1v[2 * m2 + 1]);
    }
    unsigned ys[8];
#pragma unroll
    for (int m2 = 0; m2 < 8; ++m2) {
      const int q_ = m2 >> 1, h_ = m2 & 1;
      const unsigned xs = lh ? u[4 * q_ + h_] : u[4 * q_ + 2 + h_];
      ys[m2] = __shfl_xor(xs, 32);
    }
    f16x8 pf[4];
#pragma unroll
    for (int kk = 0; kk < 4; ++kk) {
      union { u32x4 u4; f16x8 h8; } cv;
      if (lh == 0) {
        cv.u4[0] = u[4 * kk];     cv.u4[1] = u[4 * kk + 1];
        cv.u4[2] = ys[2 * kk];    cv.u4[3] = ys[2 * kk + 1];
      } else {
        cv.u4[0] = ys[2 * kk];    cv.u4[1] = ys[2 * kk + 1];
        cv.u4[2] = u[4 * kk + 2]; cv.u4[3] = u[4 * kk + 3];
      }
      pf[kk] = cv.h8;
    }

    __builtin_amdgcn_s_setprio(1);
#pragma unroll
    for (int ct = 0; ct < 4; ++ct) {
      const int dcol = ct * 32 + lm;
#pragma unroll
      for (int kk = 0; kk < 4; ++kk) {
        const int gv = (2 * kk + lh) ^ (dcol & 7);
        const f16x8 bv = *(const f16x8*)&Vs[dcol * 64 + 8 * gv];
        acc[ct] = __builtin_amdgcn_mfma_f32_32x32x16_f16(pf[kk], bv, acc[ct], 0, 0, 0);
      }
    }
    __builtin_amdgcn_s_setprio(0);
  }

  const int bb = bh >> 4, hh = bh & 15;
  const float inv = 1.f / sr;
#pragma unroll
  for (int j = 0; j < 16; ++j) {
    const int rl = (j & 3) + 8 * (j >> 2) + 4 * lh;
    const float invj = __shfl(inv, rl);
    const size_t row = (size_t)(bb * 2048 + wrow0 + rl);
#pragma unroll
    for (int ct = 0; ct < 4; ++ct)
      op[row * 2048 + hh * 128 + ct * 32 + lm] = (f16)(acc[ct][j] * invj);
  }
}

extern "C" void kernel_launch(void* const* d_in, const int* in_sizes, int n_in,
                              void* d_out, int out_size, void* d_ws, size_t ws_size,
                              hipStream_t stream) {
  const float* x   = (const float*)d_in[0];
  const float* Wq  = (const float*)d_in[2];
  const float* Wk  = (const float*)d_in[3];
  const float* Wv  = (const float*)d_in[4];
  const float* Wo  = (const float*)d_in[5];
  const float* Wup = (const float*)d_in[6];
  const float* bup = (const float*)d_in[7];
  const float* Wdn = (const float*)d_in[8];
  float* out = (float*)d_out;

  const size_t M1 = 1u << 20;
  f16* W = (f16*)d_ws;
  f16* x_hi    = W + 0 * M1;
  f16* wqkv_hi = W + 8 * M1;
  f16* wo_hi   = W + 20 * M1;
  f16* wup_hi  = W + 24 * M1;
  f16* wdn_hi  = W + 40 * M1;
  f16* q_hi    = W + 56 * M1;
  f16* q_lo    = W + 72 * M1;
  f16* vp      = W + 88 * M1;
  f16* vtb     = W + 96 * M1;
  f16* x1b   = x_hi;
  float* p0  = (float*)(W + 24 * M1);
  f16* hb    = W + 56 * M1;
  float* p1  = (float*)(W + 88 * M1);
  f16* attno = vp;
  if (ws_size < (size_t)104 * M1 * sizeof(f16)) return;  // 208 MB

  auto cg = [](size_t n4) { size_t g = (n4 + 255) / 256; return (unsigned)(g > 2048 ? 2048 : g); };
  dim3 b256(256);
  dim3 b512(512);
  k_cast<<<cg(2 * M1), b256, 0, stream>>>(x, x_hi, (int)(2 * M1));
  k_cast4<<<dim3(cg(1 * M1), 4), b256, 0, stream>>>(
      Wq, Wk, Wv, Wo,
      wqkv_hi, wqkv_hi + 4 * M1, wqkv_hi + 8 * M1, wo_hi, (int)(1 * M1));
  k_cast2w<<<dim3(cg(4 * M1), 2), b256, 0, stream>>>(
      Wup, Wdn, wup_hi, wdn_hi, (int)(4 * M1));

  // fused Q+K+V projection: 256x256 8-phase, split (hi+lo) OUTPUT for Q,K.
  gemm9<0, 1><<<dim3(24, 16), b512, 0, stream>>>(
      x_hi, wqkv_hi, 2048, 2048, 6144,
      nullptr, nullptr, nullptr, q_hi, q_lo, vp);
  k_transpose_v<<<dim3(32, 2, 32), b256, 0, stream>>>(vp, vtb);
  k_attn<<<dim3(512), b256, 0, stream>>>(
      q_hi, q_lo, q_hi + 8 * M1, q_lo + 8 * M1, vtb, attno);
  // Wo projection + residual -> x1b (f16), legacy 128^2 kernel
  gemm_nt<1, 0, 64><<<dim3(16, 32), b256, 0, stream>>>(
      attno, wo_hi, 2048, 2048, 2048, x, x1b);
  // Up + bias + relu -> hb
  gemm9<2, 0><<<dim3(32, 16), b512, 0, stream>>>(
      x1b, wup_hi, 2048, 2048, 8192,
      bup, nullptr, nullptr, hb, nullptr, nullptr);
  // Down, K split 2x -> f32 partials
  gemm9<3, 0><<<dim3(8, 16, 2), b512, 0, stream>>>(
      hb, wdn_hi, 4096, 8192, 2048,
      nullptr, p0, p1, nullptr, nullptr, nullptr);
  // out = f32(x1b) + p0 + p1
  k_fuseout<<<2048, b256, 0, stream>>>(x1b, p0, p1, out, (int)(2 * M1));
}

// Round 24
// 686.326 us; speedup vs baseline: 1.0239x; 1.0113x over previous
//
#include <hip/hip_runtime.h>
#include <stdint.h>

typedef _Float16 f16;
typedef __attribute__((ext_vector_type(8))) _Float16 f16x8;
typedef __attribute__((ext_vector_type(4))) _Float16 f16x4;
typedef __attribute__((ext_vector_type(2))) __fp16 fp16x2;
typedef __attribute__((ext_vector_type(4))) float f32x4;
typedef __attribute__((ext_vector_type(16))) float f32x16;
typedef __attribute__((ext_vector_type(4))) unsigned u32x4;

// async global->LDS, 16B per lane. LDS dest is wave-uniform base (+lane*16 in HW).
__device__ __forceinline__ void gload16(void* lds, const void* gc) {
  void* g = const_cast<void*>(gc);
  __builtin_amdgcn_global_load_lds((__attribute__((address_space(1))) void*)g,
                                   (__attribute__((address_space(3))) void*)lds,
                                   16, 0, 0);
}

__device__ __forceinline__ unsigned pkrtz(float a, float b) {
  union { fp16x2 h; unsigned u; } c;
  c.h = __builtin_amdgcn_cvt_pkrtz(a, b);
  return c.u;
}

// ---------------- fused f32 -> f16 cast: 7 jobs in one launch ----------------
__global__ __launch_bounds__(256) void k_cast_all(
    const float* __restrict__ s0, const float* __restrict__ s1,
    const float* __restrict__ s2, const float* __restrict__ s3,
    const float* __restrict__ s4, const float* __restrict__ s5,
    const float* __restrict__ s6,
    f16* __restrict__ d0, f16* __restrict__ d1, f16* __restrict__ d2,
    f16* __restrict__ d3, f16* __restrict__ d4, f16* __restrict__ d5,
    f16* __restrict__ d6) {
  const int which = blockIdx.y;
  const float* in;
  f16* out;
  int n4;
  switch (which) {
    case 0: in = s0; out = d0; n4 = 2 << 20; break;  // x      (8M elems)
    case 1: in = s1; out = d1; n4 = 1 << 20; break;  // Wq
    case 2: in = s2; out = d2; n4 = 1 << 20; break;  // Wk
    case 3: in = s3; out = d3; n4 = 1 << 20; break;  // Wv
    case 4: in = s4; out = d4; n4 = 1 << 20; break;  // Wo
    case 5: in = s5; out = d5; n4 = 4 << 20; break;  // Wup
    default: in = s6; out = d6; n4 = 4 << 20; break; // Wdn
  }
  int stride = gridDim.x * blockDim.x;
  for (int i = blockIdx.x * blockDim.x + threadIdx.x; i < n4; i += stride) {
    float4 v = ((const float4*)in)[i];
    f16x4 o;
    o[0] = (f16)v.x; o[1] = (f16)v.y; o[2] = (f16)v.z; o[3] = (f16)v.w;
    ((f16x4*)out)[i] = o;
  }
}

// ---------------- V transpose: [BH][L][128] -> [BH][128][L] ----------------
__global__ __launch_bounds__(256) void k_transpose_v(const f16* __restrict__ vp,
                                                     f16* __restrict__ vt) {
  __shared__ __attribute__((aligned(16))) f16 tile[64][66];
  const int lt = blockIdx.x, dt = blockIdx.y, bh = blockIdx.z;
  const int t = threadIdx.x;
  const int r = t >> 3, c = 8 * (t & 7);
  const f16* src = vp + ((size_t)bh * 2048 + lt * 64) * 128 + dt * 64;
#pragma unroll
  for (int i = 0; i < 2; ++i) {
    union { f16x8 v; unsigned u[4]; } uu;
    uu.v = *(const f16x8*)&src[(size_t)(i * 32 + r) * 128 + c];
#pragma unroll
    for (int j = 0; j < 4; ++j)
      *(unsigned*)&tile[i * 32 + r][c + 2 * j] = uu.u[j];
  }
  __syncthreads();
  f16* dst = vt + ((size_t)bh * 128 + dt * 64) * 2048 + lt * 64;
#pragma unroll
  for (int i = 0; i < 2; ++i) {
    const int dr = i * 32 + r;
    f16x8 o;
#pragma unroll
    for (int e = 0; e < 8; ++e) o[e] = tile[c + e][dr];
    *(f16x8*)&dst[(size_t)dr * 2048 + c] = o;
  }
}

// ---------------- final fuse: out = f32(x1b) + p0 + p1 ----------------
__global__ __launch_bounds__(256) void k_fuseout(const f16* __restrict__ x1b,
                                                 const float* __restrict__ p0,
                                                 const float* __restrict__ p1,
                                                 float* __restrict__ out, int n4) {
  int stride = gridDim.x * blockDim.x;
  for (int i = blockIdx.x * blockDim.x + threadIdx.x; i < n4; i += stride) {
    float4 a = ((const float4*)p0)[i];
    float4 b = ((const float4*)p1)[i];
    f16x4 xb = ((const f16x4*)x1b)[i];
    float4 o;
    o.x = (float)xb[0] + a.x + b.x;
    o.y = (float)xb[1] + a.y + b.y;
    o.z = (float)xb[2] + a.z + b.z;
    o.w = (float)xb[3] + a.w + b.w;
    ((float4*)out)[i] = o;
  }
}

// ---------------- legacy 128x128 NT GEMM (kept for Wo) ----------------
template <int EPI, int SPLITOUT, int BK>
__global__ __launch_bounds__(256, 4) void gemm_nt(const f16* __restrict__ A,
                                                  const f16* __restrict__ B,
                                                  int Kit, int ld, int N,
                                                  const float* __restrict__ res,
                                                  f16* __restrict__ outb) {
  constexpr int TSZ = 128 * BK;
  constexpr int CH  = 2048;
  constexpr int RPC = CH / BK;
  constexpr int NCH = 128 / RPC;
  constexpr int CW  = BK / 8;
  __shared__ __attribute__((aligned(16))) f16 As[TSZ];
  __shared__ __attribute__((aligned(16))) f16 Bs[TSZ];
  const int t = threadIdx.x;
  const int l = t & 63;
  const int w = t >> 6;
  const int wr = w >> 1, wc = w & 1;

  const int nwg = gridDim.x * gridDim.y;
  const int id = blockIdx.y * gridDim.x + blockIdx.x;
  const int sw = (id & 7) * (nwg >> 3) + (id >> 3);
  const int bn = sw % gridDim.x;
  const int bm = sw / gridDim.x;

  f32x4 acc[4][4] = {};

  const size_t aoff = (size_t)bm * 128 * ld;
  const size_t boff = (size_t)bn * 128 * ld;

  const int sr = t / CW;
  const int sc = 8 * (t % CW);
  const int lbase = w * 512;

  const int lr = l & 15, lq = l >> 4;
  const int nk = Kit / BK;
  for (int kt = 0; kt < nk; ++kt) {
    const size_t gbase = (size_t)kt * BK + (size_t)sr * ld + sc;
#pragma unroll
    for (int j = 0; j < NCH; ++j) {
      gload16(As + j * CH + lbase, A + aoff + (size_t)j * RPC * ld + gbase);
      gload16(Bs + j * CH + lbase, B + boff + (size_t)j * RPC * ld + gbase);
    }
    __syncthreads();
#pragma unroll
    for (int kk = 0; kk < BK / 32; ++kk) {
      f16x8 af[4], bfr[4];
#pragma unroll
      for (int m = 0; m < 4; ++m)
        af[m] = *(const f16x8*)&As[(wr * 64 + m * 16 + lr) * BK + kk * 32 + 8 * lq];
#pragma unroll
      for (int n = 0; n < 4; ++n)
        bfr[n] = *(const f16x8*)&Bs[(wc * 64 + n * 16 + lr) * BK + kk * 32 + 8 * lq];
#pragma unroll
      for (int m = 0; m < 4; ++m)
#pragma unroll
        for (int n = 0; n < 4; ++n)
          acc[m][n] = __builtin_amdgcn_mfma_f32_16x16x32_f16(af[m], bfr[n], acc[m][n], 0, 0, 0);
    }
    __syncthreads();
  }

#pragma unroll
  for (int m = 0; m < 4; ++m) {
#pragma unroll
    for (int r = 0; r < 4; ++r) {
      const int grow = bm * 128 + wr * 64 + m * 16 + lq * 4 + r;
#pragma unroll
      for (int n = 0; n < 4; ++n) {
        const int gcol = bn * 128 + wc * 64 + n * 16 + lr;
        const size_t idx = (size_t)grow * N + gcol;
        outb[idx] = (f16)(res[idx] + acc[m][n][r]);
      }
    }
  }
}

// ---------------- 256x256 BK=64 8-phase pipelined NT GEMM (m201 port) ----------------
template <int EPI, int SPLITOUT>
__global__ __launch_bounds__(512) void gemm9(const f16* __restrict__ A,
                                             const f16* __restrict__ B,
                                             int Kit, int ld, int N,
                                             const float* __restrict__ bias,
                                             float* __restrict__ outf,
                                             float* __restrict__ outf2,
                                             f16* __restrict__ outb,
                                             f16* __restrict__ outb_lo,
                                             f16* __restrict__ outv) {
  __shared__ __attribute__((aligned(16))) f16 As[32768];
  __shared__ __attribute__((aligned(16))) f16 Bs[32768];
  const int t = threadIdx.x;
  const int l = t & 63;
  const int w = t >> 6;
  const int wm = w >> 2, wn = w & 3;

  const int nwg = gridDim.x * gridDim.y;
  const int id = blockIdx.y * gridDim.x + blockIdx.x;
  const int sw = (id & 7) * (nwg >> 3) + (id >> 3);
  const int bn = sw % gridDim.x;
  const int bm = sw / gridDim.x;
  const int k0 = blockIdx.z * Kit;

  const size_t aoff = (size_t)(bm * 256) * ld + k0;
  const size_t boff = (size_t)(bn * 256) * ld + k0;

  const int r0a = t >> 3;
  const int gsw = (t & 7) ^ (r0a & 7);
  const int ldsb = (t >> 6) * 512;

  auto stageA = [&](int tile, int half) {
    const size_t col = (size_t)tile * 64 + gsw * 8;
#pragma unroll
    for (int j = 0; j < 2; ++j)
      gload16(As + (tile & 1) * 16384 + half * 8192 + j * 4096 + ldsb,
              A + aoff + (size_t)(half * 128 + j * 64 + r0a) * ld + col);
  };
  auto stageB = [&](int tile, int half) {
    const size_t col = (size_t)tile * 64 + gsw * 8;
#pragma unroll
    for (int j = 0; j < 2; ++j)
      gload16(Bs + (tile & 1) * 16384 + half * 8192 + j * 4096 + ldsb,
              B + boff + (size_t)(half * 128 + j * 64 + r0a) * ld + col);
  };

  f32x4 acc[8][4] = {};
  f16x8 af[4][2], bf[4][2];

  const int lr = l & 15, lq = l >> 4;

  auto dsA = [&](int buf, int mh) {
#pragma unroll
    for (int m = 0; m < 4; ++m) {
      const int row = mh * 64 + m * 16 + lr;
#pragma unroll
      for (int ks = 0; ks < 2; ++ks) {
        const int g = (ks * 4 + lq) ^ (row & 7);
        af[m][ks] = *(const f16x8*)&As[buf * 16384 + wm * 8192 + row * 64 + g * 8];
      }
    }
  };
  auto dsB = [&](int buf, int nh) {
#pragma unroll
    for (int n2 = 0; n2 < 2; ++n2) {
      const int row = (wn & 1) * 64 + (nh * 2 + n2) * 16 + lr;
#pragma unroll
      for (int ks = 0; ks < 2; ++ks) {
        const int g = (ks * 4 + lq) ^ (row & 7);
        bf[nh * 2 + n2][ks] = *(const f16x8*)&Bs[buf * 16384 + (wn >> 1) * 8192 + row * 64 + g * 8];
      }
    }
  };
  auto mfma16 = [&](int mh, int nh) {
    __builtin_amdgcn_s_setprio(1);
#pragma unroll
    for (int m = 0; m < 4; ++m)
#pragma unroll
      for (int n2 = 0; n2 < 2; ++n2)
#pragma unroll
        for (int ks = 0; ks < 2; ++ks)
          acc[mh * 4 + m][nh * 2 + n2] = __builtin_amdgcn_mfma_f32_16x16x32_f16(
              af[m][ks], bf[nh * 2 + n2][ks], acc[mh * 4 + m][nh * 2 + n2], 0, 0, 0);
    __builtin_amdgcn_s_setprio(0);
  };
#define BAR() __builtin_amdgcn_s_barrier()
#define LGKM() do { asm volatile("s_waitcnt lgkmcnt(0)" ::: "memory"); \
                    __builtin_amdgcn_sched_barrier(0); } while (0)

  const int ntk = Kit >> 6;
  const int nj = ntk >> 1;

  stageA(0, 0); stageA(0, 1); stageB(0, 0); stageB(0, 1);
  stageB(1, 0); stageB(1, 1);
  asm volatile("s_waitcnt vmcnt(4)" ::: "memory");
  BAR();

  for (int j = 0; j < nj; ++j) {
    const int t1 = 2 * j + 1, t2 = 2 * j + 2, t3 = 2 * j + 3;
    const bool last = (j == nj - 1);
    // ph1
    dsA(0, 0); dsB(0, 0);
    stageA(t1, 0);
    BAR(); LGKM(); mfma16(0, 0); BAR();
    // ph2
    dsB(0, 1);
    stageA(t1, 1);
    BAR(); LGKM(); mfma16(0, 1); BAR();
    // ph3
    dsA(0, 1);
    if (t2 < ntk) stageB(t2, 0);
    BAR(); LGKM(); mfma16(1, 0); BAR();
    // ph4
    if (t2 < ntk) stageB(t2, 1);
    BAR(); mfma16(1, 1);
    if (last) { asm volatile("s_waitcnt vmcnt(0)" ::: "memory"); }
    else      { asm volatile("s_waitcnt vmcnt(4)" ::: "memory"); }
    BAR();
    // ph5
    dsA(1, 0); dsB(1, 0);
    if (t2 < ntk) stageA(t2, 0);
    BAR(); LGKM(); mfma16(0, 0); BAR();
    // ph6
    dsB(1, 1);
    if (t2 < ntk) stageA(t2, 1);
    BAR(); LGKM(); mfma16(0, 1); BAR();
    // ph7
    dsA(1, 1);
    if (t3 < ntk) stageB(t3, 0);
    BAR(); LGKM(); mfma16(1, 0); BAR();
    // ph8
    if (t3 < ntk) stageB(t3, 1);
    BAR(); mfma16(1, 1);
    if (last) { asm volatile("s_waitcnt vmcnt(0)" ::: "memory"); }
    else      { asm volatile("s_waitcnt vmcnt(4)" ::: "memory"); }
    BAR();
  }
#undef BAR
#undef LGKM

  const size_t QKS = (size_t)8 << 20;
#pragma unroll
  for (int m = 0; m < 8; ++m) {
#pragma unroll
    for (int r = 0; r < 4; ++r) {
      const int grow = bm * 256 + wm * 128 + m * 16 + lq * 4 + r;
#pragma unroll
      for (int n = 0; n < 4; ++n) {
        const int gcol = bn * 256 + wn * 64 + n * 16 + lr;
        const float v = acc[m][n][r];
        if constexpr (EPI == 0) {
          const int which = gcol >> 11;
          const int hcol = gcol & 2047;
          const int bb = grow >> 11, ll = grow & 2047;
          const int hh = hcol >> 7, dh = hcol & 127;
          const size_t idx = ((size_t)((bb * 16 + hh) * 2048 + ll) << 7) + dh;
          const f16 hv = (f16)v;
          if (which == 2) {
            outv[idx] = hv;
          } else {
            outb[which * QKS + idx] = hv;
            if constexpr (SPLITOUT) outb_lo[which * QKS + idx] = (f16)(v - (float)hv);
          }
        } else if constexpr (EPI == 2) {
          const size_t idx = (size_t)grow * N + gcol;
          outb[idx] = (f16)fmaxf(v + bias[gcol], 0.f);
        } else {
          const size_t idx = (size_t)grow * N + gcol;
          (blockIdx.z ? outf2 : outf)[idx] = v;
        }
      }
    }
  }
}

// ---------------- causal flash attention, 32x32 MFMA, swapped QK^T ----------------
__global__ __launch_bounds__(256) void k_attn(const f16* __restrict__ q_hi,
                                              const f16* __restrict__ q_lo,
                                              const f16* __restrict__ k_hi,
                                              const f16* __restrict__ k_lo,
                                              const f16* __restrict__ vtp,
                                              f16* __restrict__ op) {
  __shared__ __attribute__((aligned(16))) f16 Ks_hi[64 * 128];
  __shared__ __attribute__((aligned(16))) f16 Ks_lo[64 * 128];
  __shared__ __attribute__((aligned(16))) f16 Vs[128 * 64];
  const int t = threadIdx.x, l = t & 63, w = t >> 6;
  const int flat = (int)blockIdx.x;
  const int s_ = flat >> 5;
  const int bh = flat & 31;
  const int qb = (s_ < 8) ? (15 - s_) : (s_ - 8);
  const int q0 = qb * 128;
  const int lh = l >> 5, lm = l & 31;
  const int wrow0 = q0 + 32 * w;
  const int myrow = wrow0 + lm;

  const f16* qhp = q_hi + (size_t)bh * 2048 * 128;
  const f16* qlp = q_lo + (size_t)bh * 2048 * 128;
  const f16* khp = k_hi + (size_t)bh * 2048 * 128;
  const f16* klp = k_lo + (size_t)bh * 2048 * 128;
  const f16* vhp = vtp + (size_t)bh * 128 * 2048;

  const int krow = t >> 4, kg = t & 15;
  const int vrow = t >> 3, vg = t & 7;

  f16x8 aqh[8], aql[8];
#pragma unroll
  for (int c = 0; c < 8; ++c) {
    const size_t qi = (size_t)myrow * 128 + c * 16 + 8 * lh;
    aqh[c] = *(const f16x8*)&qhp[qi];
    aql[c] = *(const f16x8*)&qlp[qi];
  }

  f32x16 acc[4] = {};
  float mr = -1e30f, sr = 0.f;

  const int ntile = 2 * qb + 2;
  for (int kt = 0; kt < ntile; ++kt) {
    f16x8 kh2[2], kl2[2], v2[2];
#pragma unroll
    for (int i = 0; i < 2; ++i) {
      const size_t ki = (size_t)(kt * 64 + i * 16 + krow) * 128 + 8 * kg;
      kh2[i] = *(const f16x8*)&khp[ki];
      kl2[i] = *(const f16x8*)&klp[ki];
      v2[i] = *(const f16x8*)&vhp[(size_t)(i * 32 + vrow) * 2048 + kt * 64 + 8 * vg];
    }
    __syncthreads();
#pragma unroll
    for (int i = 0; i < 2; ++i) {
      const int kr = i * 16 + krow;
      const int g = kg ^ (kr & 7);
      *(f16x8*)&Ks_hi[kr * 128 + 8 * g] = kh2[i];
      *(f16x8*)&Ks_lo[kr * 128 + 8 * g] = kl2[i];
      const int vr = i * 32 + vrow;
      const int gv = vg ^ (vr & 7);
      *(f16x8*)&Vs[vr * 64 + 8 * gv] = v2[i];
    }
#pragma unroll
    for (int i = 0; i < 2; ++i) {
      const size_t ki = (size_t)(kt * 64 + (i + 2) * 16 + krow) * 128 + 8 * kg;
      kh2[i] = *(const f16x8*)&khp[ki];
      kl2[i] = *(const f16x8*)&klp[ki];
      v2[i] = *(const f16x8*)&vhp[(size_t)((i + 2) * 32 + vrow) * 2048 + kt * 64 + 8 * vg];
    }
#pragma unroll
    for (int i = 0; i < 2; ++i) {
      const int kr = (i + 2) * 16 + krow;
      const int g = kg ^ (kr & 7);
      *(f16x8*)&Ks_hi[kr * 128 + 8 * g] = kh2[i];
      *(f16x8*)&Ks_lo[kr * 128 + 8 * g] = kl2[i];
      const int vr = (i + 2) * 32 + vrow;
      const int gv = vg ^ (vr & 7);
      *(f16x8*)&Vs[vr * 64 + 8 * gv] = v2[i];
    }
    __syncthreads();

    if (kt * 64 >= wrow0 + 32) continue;

    f32x16 s0, s1;
    __builtin_amdgcn_s_setprio(1);
    {
      f32x16 zh = {}, zl = {};
#pragma unroll
      for (int c = 0; c < 8; ++c) {
        const int g = (2 * c + lh) ^ (lm & 7);
        const f16x8 bh_ = *(const f16x8*)&Ks_hi[lm * 128 + 8 * g];
        const f16x8 bl_ = *(const f16x8*)&Ks_lo[lm * 128 + 8 * g];
        zh = __builtin_amdgcn_mfma_f32_32x32x16_f16(bh_, aqh[c], zh, 0, 0, 0);
        zl = __builtin_amdgcn_mfma_f32_32x32x16_f16(bh_, aql[c], zl, 0, 0, 0);
        zl = __builtin_amdgcn_mfma_f32_32x32x16_f16(bl_, aqh[c], zl, 0, 0, 0);
      }
      s0 = zh + zl;
    }
    {
      f32x16 zh = {}, zl = {};
#pragma unroll
      for (int c = 0; c < 8; ++c) {
        const int g = (2 * c + lh) ^ (lm & 7);
        const f16x8 bh_ = *(const f16x8*)&Ks_hi[(32 + lm) * 128 + 8 * g];
        const f16x8 bl_ = *(const f16x8*)&Ks_lo[(32 + lm) * 128 + 8 * g];
        zh = __builtin_amdgcn_mfma_f32_32x32x16_f16(bh_, aqh[c], zh, 0, 0, 0);
        zl = __builtin_amdgcn_mfma_f32_32x32x16_f16(bh_, aql[c], zl, 0, 0, 0);
        zl = __builtin_amdgcn_mfma_f32_32x32x16_f16(bl_, aqh[c], zl, 0, 0, 0);
      }
      s1 = zh + zl;
    }
    __builtin_amdgcn_s_setprio(0);

    if (kt * 64 + 63 > wrow0) {
#pragma unroll
      for (int j = 0; j < 16; ++j) {
        const int keyl = (j & 3) + 8 * (j >> 2) + 4 * lh;
        if (kt * 64 + keyl > myrow) s0[j] = -1e30f;
        if (kt * 64 + 32 + keyl > myrow) s1[j] = -1e30f;
      }
    }

    float m = -1e30f;
#pragma unroll
    for (int j = 0; j < 16; ++j) m = fmaxf(m, fmaxf(s0[j], s1[j]));
    m = fmaxf(m, __shfl_xor(m, 32));
    if (__any(m > mr + 8.f)) {
      const float mnew = fmaxf(mr, m);
      const float sc = __expf(mr - mnew);
      mr = mnew;
      sr *= sc;
#pragma unroll
      for (int j = 0; j < 16; ++j) {
        const float scj = __shfl(sc, (j & 3) + 8 * (j >> 2) + 4 * lh);
#pragma unroll
        for (int ct = 0; ct < 4; ++ct) acc[ct][j] *= scj;
      }
    }
    float p0v[16], p1v[16];
    float ts = 0.f;
#pragma unroll
    for (int j = 0; j < 16; ++j) {
      p0v[j] = __expf(s0[j] - mr);
      p1v[j] = __expf(s1[j] - mr);
      ts += p0v[j] + p1v[j];
    }
    sr += ts + __shfl_xor(ts, 32);

    unsigned u[16];
#pragma unroll
    for (int m2 = 0; m2 < 8; ++m2) {
      u[m2] = pkrtz(p0v[2 * m2], p0v[2 * m2 + 1]);
      u[8 + m2] = pkrtz(p1v[2 * m2], p1v[2 * m2 + 1]);
    }
    unsigned ys[8];
#pragma unroll
    for (int m2 = 0; m2 < 8; ++m2) {
      const int q_ = m2 >> 1, h_ = m2 & 1;
      const unsigned xs = lh ? u[4 * q_ + h_] : u[4 * q_ + 2 + h_];
      ys[m2] = __shfl_xor(xs, 32);
    }
    f16x8 pf[4];
#pragma unroll
    for (int kk = 0; kk < 4; ++kk) {
      union { u32x4 u4; f16x8 h8; } cv;
      if (lh == 0) {
        cv.u4[0] = u[4 * kk];     cv.u4[1] = u[4 * kk + 1];
        cv.u4[2] = ys[2 * kk];    cv.u4[3] = ys[2 * kk + 1];
      } else {
        cv.u4[0] = ys[2 * kk];    cv.u4[1] = ys[2 * kk + 1];
        cv.u4[2] = u[4 * kk + 2]; cv.u4[3] = u[4 * kk + 3];
      }
      pf[kk] = cv.h8;
    }

    __builtin_amdgcn_s_setprio(1);
#pragma unroll
    for (int ct = 0; ct < 4; ++ct) {
      const int dcol = ct * 32 + lm;
#pragma unroll
      for (int kk = 0; kk < 4; ++kk) {
        const int gv = (2 * kk + lh) ^ (dcol & 7);
        const f16x8 bv = *(const f16x8*)&Vs[dcol * 64 + 8 * gv];
        acc[ct] = __builtin_amdgcn_mfma_f32_32x32x16_f16(pf[kk], bv, acc[ct], 0, 0, 0);
      }
    }
    __builtin_amdgcn_s_setprio(0);
  }

  const int bb = bh >> 4, hh = bh & 15;
  const float inv = 1.f / sr;
#pragma unroll
  for (int j = 0; j < 16; ++j) {
    const int rl = (j & 3) + 8 * (j >> 2) + 4 * lh;
    const float invj = __shfl(inv, rl);
    const size_t row = (size_t)(bb * 2048 + wrow0 + rl);
#pragma unroll
    for (int ct = 0; ct < 4; ++ct)
      op[row * 2048 + hh * 128 + ct * 32 + lm] = (f16)(acc[ct][j] * invj);
  }
}

extern "C" void kernel_launch(void* const* d_in, const int* in_sizes, int n_in,
                              void* d_out, int out_size, void* d_ws, size_t ws_size,
                              hipStream_t stream) {
  const float* x   = (const float*)d_in[0];
  const float* Wq  = (const float*)d_in[2];
  const float* Wk  = (const float*)d_in[3];
  const float* Wv  = (const float*)d_in[4];
  const float* Wo  = (const float*)d_in[5];
  const float* Wup = (const float*)d_in[6];
  const float* bup = (const float*)d_in[7];
  const float* Wdn = (const float*)d_in[8];
  float* out = (float*)d_out;

  const size_t M1 = 1u << 20;
  f16* W = (f16*)d_ws;
  f16* x_hi    = W + 0 * M1;
  f16* wqkv_hi = W + 8 * M1;
  f16* wo_hi   = W + 20 * M1;
  f16* wup_hi  = W + 24 * M1;
  f16* wdn_hi  = W + 40 * M1;
  f16* q_hi    = W + 56 * M1;
  f16* q_lo    = W + 72 * M1;
  f16* vp      = W + 88 * M1;
  f16* vtb     = W + 96 * M1;
  f16* x1b   = x_hi;
  float* p0  = (float*)(W + 24 * M1);
  f16* hb    = W + 56 * M1;
  float* p1  = (float*)(W + 88 * M1);
  f16* attno = vp;
  if (ws_size < (size_t)104 * M1 * sizeof(f16)) return;  // 208 MB

  dim3 b256(256);
  dim3 b512(512);
  // all 7 f32->f16 casts in one launch (jobs via blockIdx.y)
  k_cast_all<<<dim3(2048, 7), b256, 0, stream>>>(
      x, Wq, Wk, Wv, Wo, Wup, Wdn,
      x_hi, wqkv_hi, wqkv_hi + 4 * M1, wqkv_hi + 8 * M1, wo_hi, wup_hi, wdn_hi);

  // fused Q+K+V projection: 256x256 8-phase, split (hi+lo) OUTPUT for Q,K.
  gemm9<0, 1><<<dim3(24, 16), b512, 0, stream>>>(
      x_hi, wqkv_hi, 2048, 2048, 6144,
      nullptr, nullptr, nullptr, q_hi, q_lo, vp);
  k_transpose_v<<<dim3(32, 2, 32), b256, 0, stream>>>(vp, vtb);
  k_attn<<<dim3(512), b256, 0, stream>>>(
      q_hi, q_lo, q_hi + 8 * M1, q_lo + 8 * M1, vtb, attno);
  // Wo projection + residual -> x1b (f16), legacy 128^2 kernel
  gemm_nt<1, 0, 64><<<dim3(16, 32), b256, 0, stream>>>(
      attno, wo_hi, 2048, 2048, 2048, x, x1b);
  // Up + bias + relu -> hb
  gemm9<2, 0><<<dim3(32, 16), b512, 0, stream>>>(
      x1b, wup_hi, 2048, 2048, 8192,
      bup, nullptr, nullptr, hb, nullptr, nullptr);
  // Down, K split 2x -> f32 partials
  gemm9<3, 0><<<dim3(8, 16, 2), b512, 0, stream>>>(
      hb, wdn_hi, 4096, 8192, 2048,
      nullptr, p0, p1, nullptr, nullptr, nullptr);
  // out = f32(x1b) + p0 + p1
  k_fuseout<<<2048, b256, 0, stream>>>(x1b, p0, p1, out, (int)(2 * M1));
}